// Round 12
// baseline (491.627 us; speedup 1.0000x reference)
//
#include <hip/hip_runtime.h>
#include <hip/hip_bf16.h>

#define N_ROI 262144
#define FDIM  256
#define HDIM  64
#define NNET  128

#define CHUNK  64                  // ROIs per chunk (2 MFMA K-steps)
#define NCHUNK 16                  // chunks per block
#define RPB    (CHUNK * NCHUNK)    // 1024 ROIs per block
#define NBLK   (N_ROI / RPB)       // 256 blocks == 1 per CU, no tail
#define XPITCH 264                 // shorts per x row: 256 data + 8 pad (528B)
#define WPITCH 264                 // shorts per W1^T row
#define STRIP  40.0f               // overflow escape threshold

typedef __attribute__((ext_vector_type(8))) __bf16 bf16x8;
typedef __attribute__((ext_vector_type(8))) short short8;
typedef __attribute__((ext_vector_type(4))) float floatx4;

union frag_cast { short8 s; bf16x8 b; };

#define NEG_INF (-__builtin_huge_valf())

__device__ __forceinline__ unsigned fkey(float f) {
  unsigned u = __float_as_uint(f);
  return (u & 0x80000000u) ? ~u : (u | 0x80000000u);
}
__device__ __forceinline__ float fkey_inv(unsigned k) {
  unsigned u = (k & 0x80000000u) ? (k ^ 0x80000000u) : ~k;
  return __uint_as_float(u);
}
__device__ __forceinline__ unsigned short f2bf(float f) {  // RNE f32->bf16
  unsigned u = __float_as_uint(f);
  u += 0x7FFFu + ((u >> 16) & 1u);
  return (unsigned short)(u >> 16);
}
__device__ __forceinline__ float bf2f(unsigned short h) {
  return __uint_as_float(((unsigned)h) << 16);
}
// hardware packed cvt (v_cvt_pk_bf16_f32), RNE — hot staging path
__device__ __forceinline__ unsigned cvt2(float a, float b) {
  union { __hip_bfloat162 h; unsigned u; } cv;
  cv.h = __float22bfloat162_rn(make_float2(a, b));
  return cv.u;
}
// swizzled short-index into the x tile (64 rows x 256 shorts). XOR short-index
// bits 4,5 with (row>>3)&3. Scatter transpose gather (rows cc*32+quad*8+j,
// fixed col): key == quad -> the 4 quads hit 4 disjoint bank octets ->
// conflict-free. Staging (4-short) and score (8-short) keep 16B alignment.
__device__ __forceinline__ int sidx(int row, int s) {
  return row * XPITCH + (s ^ (((row >> 3) & 3) << 4));
}
// full 8-spread XOR swizzle for w1t (row-major b128 reads at row = h*16+col):
// k ^= (row&7)<<3 spreads the 8-way start-bank aliasing to 2-way (free).
// Preserves 16B alignment (bit3 of short-index = byte bit 4).
__device__ __forceinline__ int wsz(int row, int k) {
  return k ^ ((row & 7) << 3);
}

// Raw workgroup barrier: LDS ordering (lgkmcnt) but no vmcnt drain; global
// prefetch loads stay in flight across it. sched_barrier pins compiler motion.
__device__ __forceinline__ void block_bar() {
  __builtin_amdgcn_sched_barrier(0);
  asm volatile("s_waitcnt lgkmcnt(0)" ::: "memory");
  __builtin_amdgcn_s_barrier();
  __builtin_amdgcn_sched_barrier(0);
}

// ---------------- Fused kernel: 2-phase pipeline + VALU masked-A scatter ---
// R7/R8/R11 verified structure (2 barriers/chunk, deferred scatter), with the
// one-hot A LDS array replaced by compact gw words ((g<<16)|bf16(w)):
//   P1(ch): housekeeping; score MFMA (ch) (af from xl[b], bw from w1t);
//           scatter MFMA (ch-1): gwv via broadcast uint4 reads, masked A-frag
//           built with VALU cmp/select (idle pipe), x transpose gather.
//   P2(ch): wave0: w = exp(s - m[g]) (fixed m, ballot-guarded slow path)
//           -> gwlds[b][k], dent add;  all: stage ch+1 -> xl, issue pf ch+2.
// Removes per chunk from the LDS pipe: 256 A-frag b128 reads, the A-zero
// sweep, and 64 A writes. LDS 141 KB -> 105 KB. No w1f registers (the R10
// spill source): W1 stays in LDS. Fixed per-block softmax ref m is EXACT
// (cancels in num/den; finalize rescales across blocks by exp(m_b - M)).
__global__ __launch_bounds__(1024, 4) void fused_kernel(
    const float* __restrict__ x, const int* __restrict__ group,
    const float* __restrict__ W1, const float* __restrict__ b1,
    const float* __restrict__ W2,
    float* __restrict__ num_ws,   // [NNET][NBLK][FDIM]
    float* __restrict__ den_ws,   // [NNET][NBLK]
    float* __restrict__ m_ws)     // [NNET][NBLK]
{
  __shared__ __align__(16) unsigned short w1t[HDIM][WPITCH];      // 33792 B
  __shared__ __align__(16) unsigned short xl[2][CHUNK * XPITCH];  // 67584 B
  __shared__ __align__(16) unsigned gwlds[2][CHUNK];              // 512 B
  __shared__ float scpart[4][CHUNK];
  __shared__ unsigned tmax[NNET];          // slow path only
  __shared__ __align__(16) float fl[NNET]; // slow path only
  __shared__ float mrunL[NNET];
  __shared__ float dent[2][NNET];
  __shared__ int sflag[2];

  const int tid  = threadIdx.x;            // 0..1023
  const int wave = tid >> 6, lane = tid & 63;
  const int col  = lane & 15, quad = lane >> 4;
  const int h    = wave >> 2;              // hidden slice [h*16, +16)
  const int mt   = wave & 3;               // row tile  [mt*16, +16)
  const int bid  = blockIdx.x;
  const size_t rbase = (size_t)bid * RPB;

  // stage W1^T bf16 once (cold), wsz-swizzled
  {
    const int n = tid & 63, kg = tid >> 6;            // kg 0..15
#pragma unroll
    for (int p = 0; p < 2; ++p) {
      const int k0 = (p * 16 + kg) * 8;
      unsigned short tmp[8];
#pragma unroll
      for (int j = 0; j < 8; ++j) tmp[j] = f2bf(W1[(k0 + j) * HDIM + n]);
      *(short8*)&w1t[n][wsz(n, k0)] = *(short8*)tmp;
    }
  }
  if (tid < NNET) { mrunL[tid] = 0.f; dent[1][tid] = 0.f; }
  if (tid == 0) sflag[1] = 0;
  float denrun = 0.f;                      // valid for tid < NNET

  const float b1s = b1[h * 16 + col];
  const float w2s = W2[h * 16 + col];

  floatx4 acc[8];           // scatter acc: 128 groups x 16 dims (this wave)
#pragma unroll
  for (int m2 = 0; m2 < 8; ++m2) acc[m2] = (floatx4)0.f;

  const float* xb = x + rbase * FDIM;

  // prologue: load + stage chunk 0; issue chunk 1 loads (stay in flight)
  float4 pf[4];
#pragma unroll
  for (int i = 0; i < 4; ++i) pf[i] = *(const float4*)(xb + i * 4096 + tid * 4);
#pragma unroll
  for (int i = 0; i < 4; ++i) {
    const int row = i * 16 + wave;
    uint2 pk; pk.x = cvt2(pf[i].x, pf[i].y); pk.y = cvt2(pf[i].z, pf[i].w);
    *(uint2*)&xl[0][sidx(row, (tid & 63) * 4)] = pk;
  }
#pragma unroll
  for (int i = 0; i < 4; ++i)
    pf[i] = *(const float4*)(xb + 16384 + i * 4096 + tid * 4);
  block_bar();

  int gch = 0;
  for (int ch = 0; ch < NCHUNK; ++ch) {
    const int b = ch & 1;

    // ================= P1(ch): housekeeping + score(ch) + scatter(ch-1) ===
    if (sflag[b ^ 1]) {                    // rare: rescale to new m
#pragma unroll
      for (int m2 = 0; m2 < 8; ++m2) {
        const floatx4 f4 = *(const floatx4*)&fl[m2 * 16 + quad * 4];
#pragma unroll
        for (int r = 0; r < 4; ++r) acc[m2][r] *= f4[r];
      }
      if (tid < NNET) denrun *= fl[tid];
    }
    if (tid < NNET) {
      denrun += dent[b ^ 1][tid];          // dent(ch-1), new-m safe
      tmax[tid] = 0u; dent[b][tid] = 0.f;
    }
    if (tid == 0) sflag[b] = 0;
    if (tid < CHUNK) gch = group[rbase + ch * CHUNK + tid];  // for P2(ch)

    // ---- score(ch): wave = (hidden h, row-tile mt) on xl[b]
    floatx4 accS = (floatx4)0.f;
#pragma unroll
    for (int c = 0; c < 8; ++c) {
      frag_cast af, bw;
      af.s = *(const short8*)&xl[b][sidx(mt * 16 + col, c * 32 + quad * 8)];
      bw.s = *(const short8*)&w1t[h * 16 + col][wsz(h * 16 + col, c * 32 + quad * 8)];
      accS = __builtin_amdgcn_mfma_f32_16x16x32_bf16(af.b, bw.b, accS, 0, 0, 0);
    }
    {   // relu + dot W2 slice, reduce over 16 cols (b2 cancels in softmax)
      float pr[4];
#pragma unroll
      for (int r = 0; r < 4; ++r) pr[r] = fmaxf(accS[r] + b1s, 0.f) * w2s;
#pragma unroll
      for (int off = 1; off < 16; off <<= 1)
#pragma unroll
        for (int r = 0; r < 4; ++r) pr[r] += __shfl_xor(pr[r], off, 16);
      if (col == 0) {
#pragma unroll
        for (int r = 0; r < 4; ++r) scpart[h][mt * 16 + quad * 4 + r] = pr[r];
      }
    }

    // ---- scatter(ch-1): gw broadcast reads + VALU masked-A + x gather
    if (ch > 0) {
#pragma unroll
      for (int cc = 0; cc < 2; ++cc) {
        unsigned gwv[8];                   // broadcast uint4 reads (free)
        *(uint4*)&gwv[0] = *(const uint4*)&gwlds[b ^ 1][cc * 32 + quad * 8];
        *(uint4*)&gwv[4] = *(const uint4*)&gwlds[b ^ 1][cc * 32 + quad * 8 + 4];
        frag_cast bfx;
        {
          unsigned short bb[8];
#pragma unroll
          for (int j = 0; j < 8; ++j)
            bb[j] = xl[b ^ 1][sidx(cc * 32 + quad * 8 + j, wave * 16 + col)];
          bfx.s = *(short8*)bb;
        }
#pragma unroll
        for (int m2 = 0; m2 < 8; ++m2) {
          const unsigned gt = (unsigned)(m2 * 16 + col);
          unsigned short aa[8];
#pragma unroll
          for (int j = 0; j < 8; ++j) {
            const unsigned g2 = gwv[j];
            aa[j] = ((g2 >> 16) == gt) ? (unsigned short)g2 : (unsigned short)0;
          }
          frag_cast af; af.s = *(short8*)aa;
          acc[m2] = __builtin_amdgcn_mfma_f32_16x16x32_bf16(af.b, bfx.b, acc[m2], 0, 0, 0);
        }
      }
    }
    block_bar();                     // end P1: scpart/zeroes visible; reads done

    // ================= P2(ch): wave0 softmax(ch) + stage(ch+1) ============
    if (tid < CHUNK) {               // wave 0 only: lane-parallel softmax
      const float s = scpart[0][tid] + scpart[1][tid] + scpart[2][tid] + scpart[3][tid];
      const float m = mrunL[gch];
      const bool trip = !(s - m <= STRIP);         // NaN-safe
      const unsigned long long bal = __ballot(trip);
      if (bal == 0ull) {             // fast path: fixed ref, no reduce
        const float w = __expf(s - m);             // w <= e^STRIP
        const unsigned short wb = f2bf(w);
        gwlds[b][tid] = ((unsigned)gch << 16) | wb;
        atomicAdd(&dent[b][gch], bf2f(wb));        // denom = same rounded w
      } else {                       // slow path: wave-internal online max
        atomicMax(&tmax[gch], fkey(s));
        asm volatile("s_waitcnt lgkmcnt(0)" ::: "memory");
#pragma unroll
        for (int hh = 0; hh < 2; ++hh) {           // lane owns g=tid, tid+64
          const int gi = tid + hh * 64;
          const unsigned tk = tmax[gi];
          float f = 1.f;
          if (tk) {
            const float mo = mrunL[gi];
            const float mn = fmaxf(mo, fkey_inv(tk));
            f = __expf(mo - mn);
            mrunL[gi] = mn;
          }
          fl[gi] = f;
        }
        asm volatile("s_waitcnt lgkmcnt(0)" ::: "memory");
        {
          const float w = __expf(s - mrunL[gch]);
          const unsigned short wb = f2bf(w);
          gwlds[b][tid] = ((unsigned)gch << 16) | wb;
          atomicAdd(&dent[b][gch], bf2f(wb));
        }
        if (tid == 0) sflag[b] = 1;
      }
    }
    if (ch < NCHUNK - 1) {           // stage pf (= chunk ch+1) -> xl[b^1]
#pragma unroll
      for (int i = 0; i < 4; ++i) {
        const int row = i * 16 + wave;
        uint2 pk; pk.x = cvt2(pf[i].x, pf[i].y); pk.y = cvt2(pf[i].z, pf[i].w);
        *(uint2*)&xl[b ^ 1][sidx(row, (tid & 63) * 4)] = pk;
      }
      if (ch < NCHUNK - 2) {         // issue chunk ch+2 loads: full period of flight
#pragma unroll
        for (int i = 0; i < 4; ++i)
          pf[i] = *(const float4*)(xb + (size_t)(ch + 2) * 16384 + i * 4096 + tid * 4);
      }
    }
    block_bar();                     // end P2: gw/dent/stage visible
  }

  // ================= epilogue: final slow-path + scatter(NCHUNK-1) ========
  {
    const int b = (NCHUNK - 1) & 1;  // = 1
    if (sflag[b]) {
#pragma unroll
      for (int m2 = 0; m2 < 8; ++m2) {
        const floatx4 f4 = *(const floatx4*)&fl[m2 * 16 + quad * 4];
#pragma unroll
        for (int r = 0; r < 4; ++r) acc[m2][r] *= f4[r];
      }
      if (tid < NNET) denrun *= fl[tid];
    }
    if (tid < NNET) denrun += dent[b][tid];
#pragma unroll
    for (int cc = 0; cc < 2; ++cc) {
      unsigned gwv[8];
      *(uint4*)&gwv[0] = *(const uint4*)&gwlds[b][cc * 32 + quad * 8];
      *(uint4*)&gwv[4] = *(const uint4*)&gwlds[b][cc * 32 + quad * 8 + 4];
      frag_cast bfx;
      {
        unsigned short bb[8];
#pragma unroll
        for (int j = 0; j < 8; ++j)
          bb[j] = xl[b][sidx(cc * 32 + quad * 8 + j, wave * 16 + col)];
        bfx.s = *(short8*)bb;
      }
#pragma unroll
      for (int m2 = 0; m2 < 8; ++m2) {
        const unsigned gt = (unsigned)(m2 * 16 + col);
        unsigned short aa[8];
#pragma unroll
        for (int j = 0; j < 8; ++j) {
          const unsigned g2 = gwv[j];
          aa[j] = ((g2 >> 16) == gt) ? (unsigned short)g2 : (unsigned short)0;
        }
        frag_cast af; af.s = *(short8*)aa;
        acc[m2] = __builtin_amdgcn_mfma_f32_16x16x32_bf16(af.b, bfx.b, acc[m2], 0, 0, 0);
      }
    }
  }

  // ---- store per-block partials, [g][b][d] layout (finalize streams it)
#pragma unroll
  for (int m2 = 0; m2 < 8; ++m2)
#pragma unroll
    for (int r = 0; r < 4; ++r) {
      const int g = m2 * 16 + quad * 4 + r;
      num_ws[((size_t)g * NBLK + bid) * FDIM + wave * 16 + col] = acc[m2][r];
    }
  if (tid < NNET) {
    den_ws[(size_t)tid * NBLK + bid] = denrun;
    m_ws[(size_t)tid * NBLK + bid]   = mrunL[tid];
  }
}

// ---------------- Finalize: global max per group + rescaled reduction ------
// 128 blocks (one per group) x 256 thr; num read is fully contiguous.
__global__ __launch_bounds__(256) void finalize_kernel(
    const float* __restrict__ num_ws, const float* __restrict__ den_ws,
    const float* __restrict__ m_ws, float* __restrict__ out)
{
  const int g   = blockIdx.x;
  const int tid = threadIdx.x;       // 256: b index phase 1; d phase 2
  __shared__ float e_l[NBLK];
  __shared__ float red[8];

  // phase 1: global max over the 256 block refs
  const float mb = m_ws[(size_t)g * NBLK + tid];
  float M = mb;
#pragma unroll
  for (int off = 1; off < 64; off <<= 1) M = fmaxf(M, __shfl_xor(M, off));
  if ((tid & 63) == 0) red[tid >> 6] = M;
  __syncthreads();
  M = fmaxf(fmaxf(red[0], red[1]), fmaxf(red[2], red[3]));

  const float eb = (mb == NEG_INF) ? 0.f : __expf(mb - M);
  e_l[tid] = eb;
  float dp = den_ws[(size_t)g * NBLK + tid] * eb;
#pragma unroll
  for (int off = 1; off < 64; off <<= 1) dp += __shfl_xor(dp, off);
  if ((tid & 63) == 0) red[4 + (tid >> 6)] = dp;
  __syncthreads();
  const float den = red[4] + red[5] + red[6] + red[7];

  // phase 2: num reduction over 256 blocks, contiguous in d
  float nsum = 0.f;
  const float* base = num_ws + (size_t)g * NBLK * FDIM + tid;
#pragma unroll 8
  for (int b = 0; b < NBLK; ++b)
    nsum += base[(size_t)b * FDIM] * e_l[b];
  out[g * FDIM + tid] = (den > 0.f) ? nsum / fmaxf(den, 1e-30f) : 0.f;
}

extern "C" void kernel_launch(void* const* d_in, const int* in_sizes, int n_in,
                              void* d_out, int out_size, void* d_ws, size_t ws_size,
                              hipStream_t stream)
{
  const float* x     = (const float*)d_in[0];
  const int*   group = (const int*)d_in[1];
  const float* W1    = (const float*)d_in[2];
  const float* b1    = (const float*)d_in[3];
  const float* W2    = (const float*)d_in[4];
  // d_in[5] = b2: cancels exactly in exp(score-ref)/sum -> unused
  float* out = (float*)d_out;

  // workspace: num[128][256][256] | den[128][256] | m[128][256] — fully
  // overwritten by fused_kernel, no memset needed.
  float* num_ws = (float*)d_ws;
  float* den_ws = num_ws + (size_t)NNET * NBLK * FDIM;
  float* m_ws   = den_ws + (size_t)NNET * NBLK;

  fused_kernel<<<NBLK, 1024, 0, stream>>>(x, group, W1, b1, W2, num_ws, den_ws, m_ws);
  finalize_kernel<<<NNET, 256, 0, stream>>>(num_ws, den_ws, m_ws, out);

  (void)in_sizes; (void)n_in; (void)out_size; (void)ws_size;
}

// Round 13
// 375.398 us; speedup vs baseline: 1.3096x; 1.3096x over previous
//
#include <hip/hip_runtime.h>
#include <hip/hip_bf16.h>

#define N_ROI 262144
#define FDIM  256
#define HDIM  64
#define NNET  128

#define CHUNK  64                  // ROIs per chunk (2 MFMA K-steps)
#define NCHUNK 16                  // chunks per block
#define RPB    (CHUNK * NCHUNK)    // 1024 ROIs per block
#define NBLK   (N_ROI / RPB)       // 256 blocks == 1 per CU, no tail
#define XPITCH 264                 // shorts per x row: 256 data + 8 pad (528B)
#define WPITCH 264                 // shorts per W1^T row
#define APITCH 72                  // shorts per one-hot A row: 64 data + 8 pad
#define STRIP  40.0f               // overflow escape threshold

typedef __attribute__((ext_vector_type(8))) __bf16 bf16x8;
typedef __attribute__((ext_vector_type(8))) short short8;
typedef __attribute__((ext_vector_type(4))) float floatx4;

union frag_cast { short8 s; bf16x8 b; };

#define NEG_INF (-__builtin_huge_valf())

__device__ __forceinline__ unsigned fkey(float f) {
  unsigned u = __float_as_uint(f);
  return (u & 0x80000000u) ? ~u : (u | 0x80000000u);
}
__device__ __forceinline__ float fkey_inv(unsigned k) {
  unsigned u = (k & 0x80000000u) ? (k ^ 0x80000000u) : ~k;
  return __uint_as_float(u);
}
__device__ __forceinline__ unsigned short f2bf(float f) {  // RNE f32->bf16
  unsigned u = __float_as_uint(f);
  u += 0x7FFFu + ((u >> 16) & 1u);
  return (unsigned short)(u >> 16);
}
__device__ __forceinline__ float bf2f(unsigned short h) {
  return __uint_as_float(((unsigned)h) << 16);
}
// hardware packed cvt (v_cvt_pk_bf16_f32), RNE — hot staging path
__device__ __forceinline__ unsigned cvt2(float a, float b) {
  union { __hip_bfloat162 h; unsigned u; } cv;
  cv.h = __float22bfloat162_rn(make_float2(a, b));
  return cv.u;
}
// swizzled short-index into the x tile (64 rows x 256 shorts). XOR short-index
// bits 4,5 with (row>>3)&3. Scatter transpose gather (rows cc*32+quad*8+j,
// fixed col): key == quad -> the 4 quads hit 4 disjoint bank octets ->
// conflict-free. Staging (4-short) and score (8-short) keep 16B alignment.
__device__ __forceinline__ int sidx(int row, int s) {
  return row * XPITCH + (s ^ (((row >> 3) & 3) << 4));
}

// Raw workgroup barrier: LDS ordering (lgkmcnt) but no vmcnt drain; global
// prefetch loads stay in flight across it. sched_barrier pins compiler motion.
__device__ __forceinline__ void block_bar() {
  __builtin_amdgcn_sched_barrier(0);
  asm volatile("s_waitcnt lgkmcnt(0)" ::: "memory");
  __builtin_amdgcn_s_barrier();
  __builtin_amdgcn_sched_barrier(0);
}

// ---------------- Fused kernel: 2-phase pipelined scores+softmax+scatter ---
// BEST VERIFIED VERSION (session round 7; measured 380.9 us total).
// 256 blocks x 1024 thr (1 block/CU, 16 waves, LDS ~141 KB, acc 32 regs).
// Software pipeline, scatter deferred one chunk; 2 barriers per chunk:
//   P1(ch): [rare slow-path rescale from P2(ch-1)] ; denrun += dent[ch-1];
//           zero A[ch&1]/tmax/dent[ch&1]/sflag[ch&1]; gch load;
//           score MFMA (ch)  ||  scatter MFMA (ch-1)   <- both in one phase
//   P2(ch): wave0: w = exp(s - m[g]) (fixed m, ballot escape) -> one-hot
//           A[ch&1], dent add;  all: stage chunk ch+1 -> xl, issue pf ch+2
// Epilogue runs the final scatter. Fixed per-block softmax ref m is EXACT
// (cancels in num/den; finalize rescales across blocks by exp(m_b - M)).
__global__ __launch_bounds__(1024, 4) void fused_kernel(
    const float* __restrict__ x, const int* __restrict__ group,
    const float* __restrict__ W1, const float* __restrict__ b1,
    const float* __restrict__ W2,
    float* __restrict__ num_ws,   // [NNET][NBLK][FDIM]
    float* __restrict__ den_ws,   // [NNET][NBLK]
    float* __restrict__ m_ws)     // [NNET][NBLK]
{
  __shared__ __align__(16) unsigned short w1t[HDIM][WPITCH];      // 33792 B
  __shared__ __align__(16) unsigned short xl[2][CHUNK * XPITCH];  // 67584 B
  __shared__ __align__(16) unsigned short Alds[2][NNET * APITCH]; // 36864 B
  __shared__ float scpart[4][CHUNK];
  __shared__ unsigned tmax[NNET];          // slow path only
  __shared__ __align__(16) float fl[NNET]; // slow path only
  __shared__ float mrunL[NNET];
  __shared__ float dent[2][NNET];
  __shared__ int sflag[2];

  const int tid  = threadIdx.x;            // 0..1023
  const int wave = tid >> 6, lane = tid & 63;
  const int col  = lane & 15, quad = lane >> 4;
  const int h    = wave >> 2;              // hidden slice [h*16, +16)
  const int mt   = wave & 3;               // row tile  [mt*16, +16)
  const int bid  = blockIdx.x;
  const size_t rbase = (size_t)bid * RPB;

  // stage W1^T bf16 once (cold)
  {
    const int n = tid & 63, kg = tid >> 6;            // kg 0..15
#pragma unroll
    for (int p = 0; p < 2; ++p) {
      const int k0 = (p * 16 + kg) * 8;
      unsigned short tmp[8];
#pragma unroll
      for (int j = 0; j < 8; ++j) tmp[j] = f2bf(W1[(k0 + j) * HDIM + n]);
      *(short8*)&w1t[n][k0] = *(short8*)tmp;
    }
  }
  if (tid < NNET) { mrunL[tid] = 0.f; dent[1][tid] = 0.f; }
  if (tid == 0) sflag[1] = 0;
  float denrun = 0.f;                      // valid for tid < NNET

  const float b1s = b1[h * 16 + col];
  const float w2s = W2[h * 16 + col];

  floatx4 acc[8];           // scatter acc: 128 groups x 16 dims (this wave)
#pragma unroll
  for (int m2 = 0; m2 < 8; ++m2) acc[m2] = (floatx4)0.f;

  const float* xb = x + rbase * FDIM;
  const short8 zero8 = (short8)0;

  // prologue: load + stage chunk 0; issue chunk 1 loads (stay in flight)
  float4 pf[4];
#pragma unroll
  for (int i = 0; i < 4; ++i) pf[i] = *(const float4*)(xb + i * 4096 + tid * 4);
#pragma unroll
  for (int i = 0; i < 4; ++i) {
    const int row = i * 16 + wave;
    uint2 pk; pk.x = cvt2(pf[i].x, pf[i].y); pk.y = cvt2(pf[i].z, pf[i].w);
    *(uint2*)&xl[0][sidx(row, (tid & 63) * 4)] = pk;
  }
#pragma unroll
  for (int i = 0; i < 4; ++i)
    pf[i] = *(const float4*)(xb + 16384 + i * 4096 + tid * 4);
  block_bar();

  int gch = 0;
  for (int ch = 0; ch < NCHUNK; ++ch) {
    const int b = ch & 1;

    // ================= P1(ch): housekeeping + score(ch) + scatter(ch-1) ===
    if (sflag[b ^ 1]) {                    // rare: rescale to new m
#pragma unroll
      for (int m2 = 0; m2 < 8; ++m2) {
        const floatx4 f4 = *(const floatx4*)&fl[m2 * 16 + quad * 4];
#pragma unroll
        for (int r = 0; r < 4; ++r) acc[m2][r] *= f4[r];
      }
      if (tid < NNET) denrun *= fl[tid];
    }
    if (tid < NNET) denrun += dent[b ^ 1][tid];   // dent(ch-1), new-m safe

    if (tid < CHUNK) gch = group[rbase + ch * CHUNK + tid];  // for P2(ch)
    // zero A[b] / tmax / dent[b] / sflag[b] (readers all finished last P1)
    for (int k8 = tid; k8 < (NNET * APITCH) / 8; k8 += 1024)
      *(short8*)&Alds[b][k8 * 8] = zero8;
    if (tid < NNET) { tmax[tid] = 0u; dent[b][tid] = 0.f; }
    if (tid == 0) sflag[b] = 0;

    // ---- score(ch): wave = (hidden h, row-tile mt) on xl[b]
    floatx4 accS = (floatx4)0.f;
#pragma unroll
    for (int c = 0; c < 8; ++c) {
      frag_cast af, bw;
      af.s = *(const short8*)&xl[b][sidx(mt * 16 + col, c * 32 + quad * 8)];
      bw.s = *(const short8*)&w1t[h * 16 + col][c * 32 + quad * 8];
      accS = __builtin_amdgcn_mfma_f32_16x16x32_bf16(af.b, bw.b, accS, 0, 0, 0);
    }
    {   // relu + dot W2 slice, reduce over 16 cols (b2 cancels in softmax)
      float pr[4];
#pragma unroll
      for (int r = 0; r < 4; ++r) pr[r] = fmaxf(accS[r] + b1s, 0.f) * w2s;
#pragma unroll
      for (int off = 1; off < 16; off <<= 1)
#pragma unroll
        for (int r = 0; r < 4; ++r) pr[r] += __shfl_xor(pr[r], off, 16);
      if (col == 0) {
#pragma unroll
        for (int r = 0; r < 4; ++r) scpart[h][mt * 16 + quad * 4 + r] = pr[r];
      }
    }

    // ---- scatter(ch-1): wave owns dims [wave*16,+16); A[b^1], xl[b^1]
    if (ch > 0) {
#pragma unroll
      for (int cc = 0; cc < 2; ++cc) {
        frag_cast bfx;
        {
          unsigned short bb[8];
#pragma unroll
          for (int j = 0; j < 8; ++j)
            bb[j] = xl[b ^ 1][sidx(cc * 32 + quad * 8 + j, wave * 16 + col)];
          bfx.s = *(short8*)bb;
        }
#pragma unroll
        for (int m2 = 0; m2 < 8; ++m2) {
          frag_cast af;   // one-hot A-frag: single aligned ds_read_b128
          af.s = *(const short8*)&Alds[b ^ 1][(m2 * 16 + col) * APITCH + cc * 32 + quad * 8];
          acc[m2] = __builtin_amdgcn_mfma_f32_16x16x32_bf16(af.b, bfx.b, acc[m2], 0, 0, 0);
        }
      }
    }
    block_bar();                     // end P1: scpart/zeroes visible; reads done

    // ================= P2(ch): wave0 softmax(ch) + stage(ch+1) ============
    if (tid < CHUNK) {               // wave 0 only: lane-parallel softmax
      const float s = scpart[0][tid] + scpart[1][tid] + scpart[2][tid] + scpart[3][tid];
      const float m = mrunL[gch];
      const bool trip = !(s - m <= STRIP);         // NaN-safe
      const unsigned long long bal = __ballot(trip);
      if (bal == 0ull) {             // fast path: fixed ref, no reduce
        const float w = __expf(s - m);             // w <= e^STRIP
        const unsigned short wb = f2bf(w);
        Alds[b][gch * APITCH + tid] = wb;          // one-hot A[g][k]
        atomicAdd(&dent[b][gch], bf2f(wb));        // denom = same rounded w
      } else {                       // slow path: wave-internal online max
        atomicMax(&tmax[gch], fkey(s));
        asm volatile("s_waitcnt lgkmcnt(0)" ::: "memory");
#pragma unroll
        for (int hh = 0; hh < 2; ++hh) {           // lane owns g=tid, tid+64
          const int gi = tid + hh * 64;
          const unsigned tk = tmax[gi];
          float f = 1.f;
          if (tk) {
            const float mo = mrunL[gi];
            const float mn = fmaxf(mo, fkey_inv(tk));
            f = __expf(mo - mn);
            mrunL[gi] = mn;
          }
          fl[gi] = f;
        }
        asm volatile("s_waitcnt lgkmcnt(0)" ::: "memory");
        {
          const float w = __expf(s - mrunL[gch]);
          const unsigned short wb = f2bf(w);
          Alds[b][gch * APITCH + tid] = wb;
          atomicAdd(&dent[b][gch], bf2f(wb));
        }
        if (tid == 0) sflag[b] = 1;
      }
    }
    if (ch < NCHUNK - 1) {           // stage pf (= chunk ch+1) -> xl[b^1]
#pragma unroll
      for (int i = 0; i < 4; ++i) {
        const int row = i * 16 + wave;
        uint2 pk; pk.x = cvt2(pf[i].x, pf[i].y); pk.y = cvt2(pf[i].z, pf[i].w);
        *(uint2*)&xl[b ^ 1][sidx(row, (tid & 63) * 4)] = pk;
      }
      if (ch < NCHUNK - 2) {         // issue chunk ch+2 loads: full period of flight
#pragma unroll
        for (int i = 0; i < 4; ++i)
          pf[i] = *(const float4*)(xb + (size_t)(ch + 2) * 16384 + i * 4096 + tid * 4);
      }
    }
    block_bar();                     // end P2: A[b]/dent[b]/stage visible
  }

  // ================= epilogue: final slow-path + scatter(NCHUNK-1) ========
  {
    const int b = (NCHUNK - 1) & 1;  // = 1
    if (sflag[b]) {
#pragma unroll
      for (int m2 = 0; m2 < 8; ++m2) {
        const floatx4 f4 = *(const floatx4*)&fl[m2 * 16 + quad * 4];
#pragma unroll
        for (int r = 0; r < 4; ++r) acc[m2][r] *= f4[r];
      }
      if (tid < NNET) denrun *= fl[tid];
    }
    if (tid < NNET) denrun += dent[b][tid];
#pragma unroll
    for (int cc = 0; cc < 2; ++cc) {
      frag_cast bfx;
      {
        unsigned short bb[8];
#pragma unroll
        for (int j = 0; j < 8; ++j)
          bb[j] = xl[b][sidx(cc * 32 + quad * 8 + j, wave * 16 + col)];
        bfx.s = *(short8*)bb;
      }
#pragma unroll
      for (int m2 = 0; m2 < 8; ++m2) {
        frag_cast af;
        af.s = *(const short8*)&Alds[b][(m2 * 16 + col) * APITCH + cc * 32 + quad * 8];
        acc[m2] = __builtin_amdgcn_mfma_f32_16x16x32_bf16(af.b, bfx.b, acc[m2], 0, 0, 0);
      }
    }
  }

  // ---- store per-block partials, [g][b][d] layout (finalize streams it)
#pragma unroll
  for (int m2 = 0; m2 < 8; ++m2)
#pragma unroll
    for (int r = 0; r < 4; ++r) {
      const int g = m2 * 16 + quad * 4 + r;
      num_ws[((size_t)g * NBLK + bid) * FDIM + wave * 16 + col] = acc[m2][r];
    }
  if (tid < NNET) {
    den_ws[(size_t)tid * NBLK + bid] = denrun;
    m_ws[(size_t)tid * NBLK + bid]   = mrunL[tid];
  }
}

// ---------------- Finalize: global max per group + rescaled reduction ------
// 128 blocks (one per group) x 256 thr; num read is fully contiguous.
__global__ __launch_bounds__(256) void finalize_kernel(
    const float* __restrict__ num_ws, const float* __restrict__ den_ws,
    const float* __restrict__ m_ws, float* __restrict__ out)
{
  const int g   = blockIdx.x;
  const int tid = threadIdx.x;       // 256: b index phase 1; d phase 2
  __shared__ float e_l[NBLK];
  __shared__ float red[8];

  // phase 1: global max over the 256 block refs
  const float mb = m_ws[(size_t)g * NBLK + tid];
  float M = mb;
#pragma unroll
  for (int off = 1; off < 64; off <<= 1) M = fmaxf(M, __shfl_xor(M, off));
  if ((tid & 63) == 0) red[tid >> 6] = M;
  __syncthreads();
  M = fmaxf(fmaxf(red[0], red[1]), fmaxf(red[2], red[3]));

  const float eb = (mb == NEG_INF) ? 0.f : __expf(mb - M);
  e_l[tid] = eb;
  float dp = den_ws[(size_t)g * NBLK + tid] * eb;
#pragma unroll
  for (int off = 1; off < 64; off <<= 1) dp += __shfl_xor(dp, off);
  if ((tid & 63) == 0) red[4 + (tid >> 6)] = dp;
  __syncthreads();
  const float den = red[4] + red[5] + red[6] + red[7];

  // phase 2: num reduction over 256 blocks, contiguous in d
  float nsum = 0.f;
  const float* base = num_ws + (size_t)g * NBLK * FDIM + tid;
#pragma unroll 8
  for (int b = 0; b < NBLK; ++b)
    nsum += base[(size_t)b * FDIM] * e_l[b];
  out[g * FDIM + tid] = (den > 0.f) ? nsum / fmaxf(den, 1e-30f) : 0.f;
}

extern "C" void kernel_launch(void* const* d_in, const int* in_sizes, int n_in,
                              void* d_out, int out_size, void* d_ws, size_t ws_size,
                              hipStream_t stream)
{
  const float* x     = (const float*)d_in[0];
  const int*   group = (const int*)d_in[1];
  const float* W1    = (const float*)d_in[2];
  const float* b1    = (const float*)d_in[3];
  const float* W2    = (const float*)d_in[4];
  // d_in[5] = b2: cancels exactly in exp(score-ref)/sum -> unused
  float* out = (float*)d_out;

  // workspace: num[128][256][256] | den[128][256] | m[128][256] — fully
  // overwritten by fused_kernel, no memset needed.
  float* num_ws = (float*)d_ws;
  float* den_ws = num_ws + (size_t)NNET * NBLK * FDIM;
  float* m_ws   = den_ws + (size_t)NNET * NBLK;

  fused_kernel<<<NBLK, 1024, 0, stream>>>(x, group, W1, b1, W2, num_ws, den_ws, m_ws);
  finalize_kernel<<<NNET, 256, 0, stream>>>(num_ws, den_ws, m_ws, out);

  (void)in_sizes; (void)n_in; (void)out_size; (void)ws_size;
}